// Round 1
// baseline (1652.892 us; speedup 1.0000x reference)
//
#include <hip/hip_runtime.h>
#include <cmath>

#define T_STEPS 1000
#define B_SZ    128
#define N_IN    85
#define N_RNN   512
#define N_OUT   33
#define K_PAD   88                      // 85 padded to 88 for float4
#define Y_SIZE  (T_STEPS * B_SZ * N_OUT)   // 4,224,000 floats

// ---------------------------------------------------------------------------
// K0: zero the diag-flag (lives at d_out[0], y-region, overwritten by head)
__global__ void k_zero_flag(int* flag) {
    if (threadIdx.x == 0 && blockIdx.x == 0) *flag = 0;
}

// ---------------------------------------------------------------------------
// K1: verify W_rec (rows 85..596 of W) is diagonal; set flag if not.
__global__ void k_check_diag(const float* __restrict__ W, int* flag) {
    const float* Wr = W + N_IN * N_RNN;
    bool bad = false;
    for (int i = blockIdx.x * blockDim.x + threadIdx.x;
         i < N_RNN * N_RNN; i += gridDim.x * blockDim.x) {
        int r = i >> 9, c = i & (N_RNN - 1);
        float v = Wr[i];
        if (r != c && v != 0.0f) bad = true;
    }
    if (bad) atomicOr(flag, 1);
}

// ---------------------------------------------------------------------------
// K2: G[row,n] = sum_k x[row,k]*W[k,n] + b[n] + noise[row,n]
// block = 256 threads, covers 64 rows x 256 n-columns. Grid 4000.
// x tile + W tile staged in LDS; 8 fp32 accumulators per thread.
__global__ __launch_bounds__(256) void k_precompute(
        const float* __restrict__ x, const float* __restrict__ W,
        const float* __restrict__ bias, const float* __restrict__ noise,
        float* __restrict__ G) {
    __shared__ float xs[64][K_PAD];        // 22,528 B
    __shared__ float wsh[K_PAD][256];      // 90,112 B
    const int tid = threadIdx.x;
    const int rc  = blockIdx.x >> 1;
    const int n0  = (blockIdx.x & 1) << 8;
    const int r0  = rc << 6;

    const float* xsrc = x + (size_t)r0 * N_IN;
    for (int i = tid; i < 64 * N_IN; i += 256) {
        int rr = i / N_IN;
        int kk = i - rr * N_IN;
        xs[rr][kk] = xsrc[i];
    }
    if (tid < 64) { xs[tid][85] = 0.f; xs[tid][86] = 0.f; xs[tid][87] = 0.f; }
    for (int i = tid; i < N_IN * 256; i += 256) {
        int kk = i >> 8, nn = i & 255;
        wsh[kk][nn] = W[kk * N_RNN + n0 + nn];
    }
    for (int i = tid; i < 3 * 256; i += 256) {
        wsh[85 + (i >> 8)][i & 255] = 0.f;
    }
    const float bn = bias[n0 + tid];
    __syncthreads();

    const int n_idx = n0 + tid;
    for (int c8 = 0; c8 < 8; ++c8) {
        const int rbase = c8 << 3;
        const size_t base_idx = (size_t)(r0 + rbase) * N_RNN + n_idx;
        float np[8];
        #pragma unroll
        for (int rr = 0; rr < 8; ++rr) np[rr] = noise[base_idx + (size_t)rr * N_RNN];
        float acc[8] = {0.f, 0.f, 0.f, 0.f, 0.f, 0.f, 0.f, 0.f};
        for (int k4 = 0; k4 < K_PAD / 4; ++k4) {
            const float w0 = wsh[4 * k4 + 0][tid];
            const float w1 = wsh[4 * k4 + 1][tid];
            const float w2 = wsh[4 * k4 + 2][tid];
            const float w3 = wsh[4 * k4 + 3][tid];
            #pragma unroll
            for (int rr = 0; rr < 8; ++rr) {
                const float4 xv = *(const float4*)&xs[rbase + rr][4 * k4];
                acc[rr] = fmaf(xv.x, w0, acc[rr]);
                acc[rr] = fmaf(xv.y, w1, acc[rr]);
                acc[rr] = fmaf(xv.z, w2, acc[rr]);
                acc[rr] = fmaf(xv.w, w3, acc[rr]);
            }
        }
        #pragma unroll
        for (int rr = 0; rr < 8; ++rr) {
            G[base_idx + (size_t)rr * N_RNN] = acc[rr] + bn + np[rr];
        }
    }
}

// ---------------------------------------------------------------------------
// K3: the scan, in-place on the h region (reads G[t], writes h[t] same addr).
// Fast path (diagonal W_rec): element-wise per (b,n), 16-deep load ring.
// Fallback: block-per-b general matvec via LDS (slow but correct).
__device__ __forceinline__ float softplus_f(float g) {
    return fmaxf(g, 0.0f) + __logf(1.0f + __expf(-fabsf(g)));
}

__global__ __launch_bounds__(512) void k_scan(const float* __restrict__ W,
                                              float* __restrict__ GH,
                                              const int* __restrict__ flag) {
    const int b = blockIdx.x;      // 128 blocks
    const int n = threadIdx.x;     // 512 threads
    const int strideT = B_SZ * N_RNN;
    float* base = GH + b * N_RNN + n;
    const float dn = W[(N_IN + n) * N_RNN + n];
    float h = 0.0f;

    if (*flag == 0) {
        float ring[16];
        #pragma unroll
        for (int i = 0; i < 16; ++i) ring[i] = base[i * strideT];
        #pragma unroll 1
        for (int tb = 0; tb < 62; ++tb) {
            const int t0 = tb << 4;
            #pragma unroll
            for (int u = 0; u < 16; ++u) {
                const int t = t0 + u;
                float g = ring[u] + dn * h;
                const int tp = t + 16;
                if (tp < T_STEPS) ring[u] = base[tp * strideT];
                const float sp = softplus_f(g);
                h = 0.8f * h + 0.2f * sp;
                base[t * strideT] = h;
            }
        }
        #pragma unroll
        for (int u = 0; u < 8; ++u) {
            const int t = 992 + u;
            float g = ring[u] + dn * h;
            const float sp = softplus_f(g);
            h = 0.8f * h + 0.2f * sp;
            base[t * strideT] = h;
        }
    } else {
        __shared__ float hs[N_RNN];
        const float* Wr = W + N_IN * N_RNN;
        for (int t = 0; t < T_STEPS; ++t) {
            hs[n] = h;
            __syncthreads();
            float g = base[t * strideT];
            for (int k = 0; k < N_RNN; ++k) {
                g = fmaf(hs[k], Wr[k * N_RNN + n], g);
            }
            const float sp = softplus_f(g);
            h = 0.8f * h + 0.2f * sp;
            base[t * strideT] = h;
            __syncthreads();
        }
    }
}

// ---------------------------------------------------------------------------
// K4: y[row,o] = sigmoid(sum_n h[row,n]*W_out[n,o] + b_out[o])
// thread-per-row (128000 = 500 blocks x 256), W_out in LDS (broadcast reads),
// 33 register accumulators.
__global__ __launch_bounds__(256) void k_head(const float* __restrict__ hbase,
                                              const float* __restrict__ Wout,
                                              const float* __restrict__ bout,
                                              float* __restrict__ y) {
    __shared__ float ws[N_RNN][36];   // stride 36 keeps float4 rows 16B-aligned
    __shared__ float bs[64];
    const int tid = threadIdx.x;
    for (int i = tid; i < N_RNN * N_OUT; i += 256) {
        int k = i / N_OUT;
        int o = i - k * N_OUT;
        ws[k][o] = Wout[i];
    }
    if (tid < N_OUT) bs[tid] = bout[tid];
    __syncthreads();

    const int row = blockIdx.x * 256 + tid;      // exactly 128000 rows
    const float* hr = hbase + (size_t)row * N_RNN;
    float acc[N_OUT];
    #pragma unroll
    for (int o = 0; o < N_OUT; ++o) acc[o] = bs[o];

    for (int k4 = 0; k4 < N_RNN / 4; ++k4) {
        const float4 hv = *(const float4*)(hr + 4 * k4);
        const float* w0 = &ws[4 * k4][0];
        #pragma unroll
        for (int j = 0; j < 4; ++j) {
            const float hx = (j == 0) ? hv.x : (j == 1) ? hv.y : (j == 2) ? hv.z : hv.w;
            const float4* wr = (const float4*)(w0 + j * 36);
            #pragma unroll
            for (int oo = 0; oo < 8; ++oo) {
                const float4 wv = wr[oo];
                acc[4 * oo + 0] = fmaf(hx, wv.x, acc[4 * oo + 0]);
                acc[4 * oo + 1] = fmaf(hx, wv.y, acc[4 * oo + 1]);
                acc[4 * oo + 2] = fmaf(hx, wv.z, acc[4 * oo + 2]);
                acc[4 * oo + 3] = fmaf(hx, wv.w, acc[4 * oo + 3]);
            }
            acc[32] = fmaf(hx, w0[j * 36 + 32], acc[32]);
        }
    }
    float* yr = y + (size_t)row * N_OUT;
    #pragma unroll
    for (int o = 0; o < N_OUT; ++o) {
        yr[o] = 1.0f / (1.0f + __expf(-acc[o]));
    }
}

// ---------------------------------------------------------------------------
extern "C" void kernel_launch(void* const* d_in, const int* in_sizes, int n_in,
                              void* d_out, int out_size, void* d_ws, size_t ws_size,
                              hipStream_t stream) {
    const float* x     = (const float*)d_in[0];  // [1000,128,85]
    const float* W     = (const float*)d_in[1];  // [597,512]
    const float* bias  = (const float*)d_in[2];  // [512]
    const float* Wout  = (const float*)d_in[3];  // [512,33]
    const float* bout  = (const float*)d_in[4];  // [33]
    const float* noise = (const float*)d_in[5];  // [1000,128,512]

    float* y  = (float*)d_out;          // y_hat region [1000,128,33]
    float* GH = y + Y_SIZE;             // h region [1000,128,512]; holds G then h
    int* flag = (int*)d_out;            // aliases y[0]; head overwrites it last

    k_zero_flag<<<1, 64, 0, stream>>>(flag);
    k_check_diag<<<256, 256, 0, stream>>>(W, flag);
    k_precompute<<<4000, 256, 0, stream>>>(x, W, bias, noise, GH);
    k_scan<<<128, 512, 0, stream>>>(W, GH, flag);
    k_head<<<500, 256, 0, stream>>>(GH, Wout, bout, y);
}

// Round 2
// 1103.929 us; speedup vs baseline: 1.4973x; 1.4973x over previous
//
#include <hip/hip_runtime.h>
#include <cmath>

#define T_STEPS 1000
#define B_SZ    128
#define N_IN    85
#define N_RNN   512
#define N_OUT   33
#define K_PAD   88                      // 85 padded to 88 for float4
#define Y_SIZE  (T_STEPS * B_SZ * N_OUT)   // 4,224,000 floats

// ---------------------------------------------------------------------------
// K0: zero the diag-flag (lives at d_out[0], y-region, overwritten by head)
__global__ void k_zero_flag(int* flag) {
    if (threadIdx.x == 0 && blockIdx.x == 0) *flag = 0;
}

// ---------------------------------------------------------------------------
// K1: verify W_rec (rows 85..596 of W) is diagonal; set flag if not.
__global__ void k_check_diag(const float* __restrict__ W, int* flag) {
    const float* Wr = W + N_IN * N_RNN;
    bool bad = false;
    for (int i = blockIdx.x * blockDim.x + threadIdx.x;
         i < N_RNN * N_RNN; i += gridDim.x * blockDim.x) {
        int r = i >> 9, c = i & (N_RNN - 1);
        float v = Wr[i];
        if (r != c && v != 0.0f) bad = true;
    }
    if (bad) atomicOr(flag, 1);
}

// ---------------------------------------------------------------------------
// K2: G[row,n] = sum_k x[row,k]*W[k,n] + b[n] + noise[row,n]
// Register-resident W column per thread (88 VGPRs), 128-row x tile in LDS
// (45 KB -> ~3 blocks/CU), broadcast float4 LDS reads, 8 accumulator chains.
// Grid: 1000 row-chunks x 2 col-halves = 2000 blocks x 256 threads.
__global__ __launch_bounds__(256) void k_precompute(
        const float* __restrict__ x, const float* __restrict__ W,
        const float* __restrict__ bias, const float* __restrict__ noise,
        float* __restrict__ G) {
    __shared__ float xs[128 * K_PAD];      // 45,056 B
    const int tid = threadIdx.x;
    const int n   = ((blockIdx.x & 1) << 8) + tid;   // output column
    const int r0  = (blockIdx.x >> 1) << 7;          // 128 rows per block

    // W column into registers (coalesced across tid per k)
    float wcol[K_PAD];
    #pragma unroll
    for (int k = 0; k < N_IN; ++k) wcol[k] = W[k * N_RNN + n];
    wcol[85] = 0.f; wcol[86] = 0.f; wcol[87] = 0.f;

    // Stage 128 x-rows into LDS (pad k=85..87 with zeros: 0*garbage = NaN risk)
    const float* xsrc = x + (size_t)r0 * N_IN;
    for (int i = tid; i < 128 * K_PAD; i += 256) {
        const int r = i / K_PAD;
        const int k = i - r * K_PAD;
        xs[i] = (k < N_IN) ? xsrc[r * N_IN + k] : 0.0f;
    }
    const float bn = bias[n];
    __syncthreads();

    for (int rb = 0; rb < 16; ++rb) {               // 16 batches of 8 rows
        const int rbase = rb << 3;
        const size_t gbase = (size_t)(r0 + rbase) * N_RNN + n;
        float np[8];
        #pragma unroll
        for (int rr = 0; rr < 8; ++rr) np[rr] = noise[gbase + (size_t)rr * N_RNN];
        float acc[8] = {0.f, 0.f, 0.f, 0.f, 0.f, 0.f, 0.f, 0.f};
        #pragma unroll
        for (int k4 = 0; k4 < K_PAD / 4; ++k4) {
            const float w0 = wcol[4 * k4 + 0];
            const float w1 = wcol[4 * k4 + 1];
            const float w2 = wcol[4 * k4 + 2];
            const float w3 = wcol[4 * k4 + 3];
            #pragma unroll
            for (int rr = 0; rr < 8; ++rr) {
                const float4 xv = *(const float4*)&xs[(rbase + rr) * K_PAD + 4 * k4];
                acc[rr] = fmaf(xv.x, w0, acc[rr]);
                acc[rr] = fmaf(xv.y, w1, acc[rr]);
                acc[rr] = fmaf(xv.z, w2, acc[rr]);
                acc[rr] = fmaf(xv.w, w3, acc[rr]);
            }
        }
        #pragma unroll
        for (int rr = 0; rr < 8; ++rr) {
            G[gbase + (size_t)rr * N_RNN] = acc[rr] + bn + np[rr];
        }
    }
}

// ---------------------------------------------------------------------------
__device__ __forceinline__ float softplus_f(float g) {
    return fmaxf(g, 0.0f) + __logf(1.0f + __expf(-fabsf(g)));
}

// K3a: diagonal-W_rec scan (fast path). Element-wise per (b,n); 512 blocks x
// 128 threads so ALL 256 CUs get work (old 128-block launch used half the
// chip). 16-deep load ring for memory-level parallelism. In-place G->h.
__global__ __launch_bounds__(128) void k_scan_fast(const float* __restrict__ W,
                                                   float* __restrict__ GH,
                                                   const int* __restrict__ flag) {
    if (*flag != 0) return;      // general path handles it
    const int b  = blockIdx.x >> 2;                 // 128 b values
    const int n  = ((blockIdx.x & 3) << 7) + threadIdx.x;  // 512 n values
    const int strideT = B_SZ * N_RNN;
    float* base = GH + b * N_RNN + n;
    const float dn = W[(N_IN + n) * N_RNN + n];
    float h = 0.0f;

    float ring[16];
    #pragma unroll
    for (int i = 0; i < 16; ++i) ring[i] = base[i * strideT];
    #pragma unroll 1
    for (int tb = 0; tb < 62; ++tb) {
        const int t0 = tb << 4;
        #pragma unroll
        for (int u = 0; u < 16; ++u) {
            const int t = t0 + u;
            float g = ring[u] + dn * h;
            const int tp = t + 16;
            if (tp < T_STEPS) ring[u] = base[tp * strideT];
            const float sp = softplus_f(g);
            h = 0.8f * h + 0.2f * sp;
            base[t * strideT] = h;
        }
    }
    #pragma unroll
    for (int u = 0; u < 8; ++u) {
        const int t = 992 + u;
        float g = ring[u] + dn * h;
        const float sp = softplus_f(g);
        h = 0.8f * h + 0.2f * sp;
        base[t * strideT] = h;
    }
}

// K3b: general W_rec fallback (block-per-b matvec). Exits immediately when
// the diagonal fast path applies.
__global__ __launch_bounds__(512) void k_scan_general(const float* __restrict__ W,
                                                      float* __restrict__ GH,
                                                      const int* __restrict__ flag) {
    if (*flag == 0) return;
    const int b = blockIdx.x;      // 128 blocks
    const int n = threadIdx.x;     // 512 threads
    const int strideT = B_SZ * N_RNN;
    float* base = GH + b * N_RNN + n;
    float h = 0.0f;
    __shared__ float hs[N_RNN];
    const float* Wr = W + N_IN * N_RNN;
    for (int t = 0; t < T_STEPS; ++t) {
        hs[n] = h;
        __syncthreads();
        float g = base[t * strideT];
        for (int k = 0; k < N_RNN; ++k) {
            g = fmaf(hs[k], Wr[k * N_RNN + n], g);
        }
        const float sp = softplus_f(g);
        h = 0.8f * h + 0.2f * sp;
        base[t * strideT] = h;
        __syncthreads();
    }
}

// ---------------------------------------------------------------------------
// K4: y[row,o] = sigmoid(sum_n h[row,n]*W_out[n,o] + b_out[o])
// thread-per-row (128000 = 500 blocks x 256), W_out in LDS (broadcast reads),
// 33 register accumulators. 74 KB LDS -> 2 blocks/CU.
__global__ __launch_bounds__(256) void k_head(const float* __restrict__ hbase,
                                              const float* __restrict__ Wout,
                                              const float* __restrict__ bout,
                                              float* __restrict__ y) {
    __shared__ float ws[N_RNN][36];   // stride 36 keeps float4 rows 16B-aligned
    __shared__ float bs[64];
    const int tid = threadIdx.x;
    for (int i = tid; i < N_RNN * N_OUT; i += 256) {
        int k = i / N_OUT;
        int o = i - k * N_OUT;
        ws[k][o] = Wout[i];
    }
    if (tid < N_OUT) bs[tid] = bout[tid];
    __syncthreads();

    const int row = blockIdx.x * 256 + tid;      // exactly 128000 rows
    const float* hr = hbase + (size_t)row * N_RNN;
    float acc[N_OUT];
    #pragma unroll
    for (int o = 0; o < N_OUT; ++o) acc[o] = bs[o];

    for (int k4 = 0; k4 < N_RNN / 4; ++k4) {
        const float4 hv = *(const float4*)(hr + 4 * k4);
        const float* w0 = &ws[4 * k4][0];
        #pragma unroll
        for (int j = 0; j < 4; ++j) {
            const float hx = (j == 0) ? hv.x : (j == 1) ? hv.y : (j == 2) ? hv.z : hv.w;
            const float4* wr = (const float4*)(w0 + j * 36);
            #pragma unroll
            for (int oo = 0; oo < 8; ++oo) {
                const float4 wv = wr[oo];
                acc[4 * oo + 0] = fmaf(hx, wv.x, acc[4 * oo + 0]);
                acc[4 * oo + 1] = fmaf(hx, wv.y, acc[4 * oo + 1]);
                acc[4 * oo + 2] = fmaf(hx, wv.z, acc[4 * oo + 2]);
                acc[4 * oo + 3] = fmaf(hx, wv.w, acc[4 * oo + 3]);
            }
            acc[32] = fmaf(hx, w0[j * 36 + 32], acc[32]);
        }
    }
    float* yr = y + (size_t)row * N_OUT;
    #pragma unroll
    for (int o = 0; o < N_OUT; ++o) {
        yr[o] = 1.0f / (1.0f + __expf(-acc[o]));
    }
}

// ---------------------------------------------------------------------------
extern "C" void kernel_launch(void* const* d_in, const int* in_sizes, int n_in,
                              void* d_out, int out_size, void* d_ws, size_t ws_size,
                              hipStream_t stream) {
    const float* x     = (const float*)d_in[0];  // [1000,128,85]
    const float* W     = (const float*)d_in[1];  // [597,512]
    const float* bias  = (const float*)d_in[2];  // [512]
    const float* Wout  = (const float*)d_in[3];  // [512,33]
    const float* bout  = (const float*)d_in[4];  // [33]
    const float* noise = (const float*)d_in[5];  // [1000,128,512]

    float* y  = (float*)d_out;          // y_hat region [1000,128,33]
    float* GH = y + Y_SIZE;             // h region [1000,128,512]; holds G then h
    int* flag = (int*)d_out;            // aliases y[0]; head overwrites it last

    k_zero_flag<<<1, 64, 0, stream>>>(flag);
    k_check_diag<<<256, 256, 0, stream>>>(W, flag);
    k_precompute<<<2000, 256, 0, stream>>>(x, W, bias, noise, GH);
    k_scan_fast<<<512, 128, 0, stream>>>(W, GH, flag);
    k_scan_general<<<128, 512, 0, stream>>>(W, GH, flag);
    k_head<<<500, 256, 0, stream>>>(GH, Wout, bout, y);
}